// Round 10
// baseline (320.086 us; speedup 1.0000x reference)
//
#include <hip/hip_runtime.h>
#include <math.h>

#define BB 2
#define TT 2048
#define DD 2048
#define HH 16
#define KVHN 4
#define HDIM 128
#define NKV 3072   // packed q|k|v row width

typedef unsigned short u16;
typedef unsigned int u32;
typedef __bf16 bf16x8 __attribute__((ext_vector_type(8)));
typedef float  f32x4  __attribute__((ext_vector_type(4)));

#define AS1 __attribute__((address_space(1)))
#define AS3 __attribute__((address_space(3)))

__device__ __forceinline__ void dma16(const u16* g, u16* l) {
  __builtin_amdgcn_global_load_lds((const AS1 u32*)g, (AS3 u32*)l, 16, 0, 0);
}

__device__ __forceinline__ u16 f2bf(float f) {
  u32 u = __float_as_uint(f);
  u32 r = (u + 0x7FFFu + ((u >> 16) & 1u)) >> 16;
  return (u16)r;
}
__device__ __forceinline__ float bf2f(u32 h) { return __uint_as_float(h << 16); }

__device__ __forceinline__ u32 pack2(float a, float b) {
  union { __bf16 h[2]; u32 u; } cv;
  cv.h[0] = (__bf16)a; cv.h[1] = (__bf16)b;
  return cv.u;
}

// HW trig: reduce to revolutions, v_sin/v_cos (D = sin(S0 * 2pi)).
// Added error ~1e-4 abs vs sincosf -- far below bf16 quantization (4e-3).
__device__ __forceinline__ void fast_sincos(float ang, float* sn, float* cs) {
  float rev = ang * 0.15915494309189535f;   // ang / 2pi
  rev -= floorf(rev);                        // [0, 1)
  float s, c;
  asm volatile("v_sin_f32 %0, %1" : "=v"(s) : "v"(rev));
  asm volatile("v_cos_f32 %0, %1" : "=v"(c) : "v"(rev));
  *sn = s; *cs = c;
}

// ---------------- cast fp32 -> bf16 ----------------------------------------
__global__ __launch_bounds__(256) void castf2b(const float* __restrict__ in,
                                               u16* __restrict__ out) {
  size_t i4 = (size_t)blockIdx.x * 256 + threadIdx.x;
  float4 v = *(const float4*)(in + i4 * 4);
  ushort4 o;
  o.x = f2bf(v.x); o.y = f2bf(v.y); o.z = f2bf(v.z); o.w = f2bf(v.w);
  *(ushort4*)(out + i4 * 4) = o;
}

// ---------------- transpose + cast: W[K][N] fp32 -> WT[N][K] bf16 ----------
__global__ __launch_bounds__(256) void tcast(const float* __restrict__ W,
                                             u16* __restrict__ WT,
                                             int K, int N) {
  __shared__ float tile[32][33];
  const int n0 = blockIdx.x * 32, k0 = blockIdx.y * 32;
  const int r = threadIdx.x >> 3;
  const int c4 = (threadIdx.x & 7) * 4;
  float4 v = *(const float4*)(W + (size_t)(k0 + r) * N + n0 + c4);
  tile[r][c4 + 0] = v.x; tile[r][c4 + 1] = v.y;
  tile[r][c4 + 2] = v.z; tile[r][c4 + 3] = v.w;
  __syncthreads();
  ushort4 o;
  o.x = f2bf(tile[c4 + 0][r]); o.y = f2bf(tile[c4 + 1][r]);
  o.z = f2bf(tile[c4 + 2][r]); o.w = f2bf(tile[c4 + 3][r]);
  *(ushort4*)(WT + (size_t)(n0 + r) * K + k0 + c4) = o;
}

// ---------------- counted-vmcnt MFMA GEMM, 128x128 / 4-wave / tri-buffer ---
// C = A @ BT^T.  BM=BN=128, BK=32, 256 thr = 4 waves (2M x 2N) -- the
// m103-validated tile (912 TF ref) on the session-proven counted-vmcnt
// skeleton.  LDS 3 x 16KB = 48KB -> 3 blocks/CU.  4 dma16/thread/tile ->
// vmcnt thresholds 8/4/0 (prefetch distance 2).  Same 64B-row 4-chunk XOR
// swizzle as the proven gemm8p, applied to pre-swizzled GLOBAL source and
// ds_read chunk.  XCD-aware bijective block swizzle: each XCD gets a
// contiguous x-major chunk -> A-panels stay L2-resident.
template <int OUT_BF16>
__global__ __launch_bounds__(256, 3) void gemmt(const u16* __restrict__ A,
                                                const u16* __restrict__ BT,
                                                void* __restrict__ Cv,
                                                int N, int K) {
  __shared__ u16 lds[3 * 8192];    // per buffer: A 128x32 (4096) | B 128x32 (4096)
  const int t = threadIdx.x;
  const int l = t & 63, w = t >> 6;
  const int lm = l & 15, quad = l >> 4;
  const int wm = w & 1, wn = w >> 1;
  // XCD swizzle (bijective: nwg % 8 == 0 for both grids: 768, 512)
  const int Nx = gridDim.x;
  const int nwg = Nx * gridDim.y;
  const int flat = blockIdx.y * Nx + blockIdx.x;
  const int cpx = nwg >> 3;
  const int swz = (flat & 7) * cpx + (flat >> 3);
  const int m0 = (swz / Nx) * 128, n0 = (swz % Nx) * 128;
  const int wu = __builtin_amdgcn_readfirstlane(w);
  const int tid = wu * 64 + l;

  // staging source pointers (pre-swizzled global col) + uniform LDS dests
  const u16* srcA[2]; int dstA[2];
  const u16* srcB[2]; int dstB[2];
  #pragma unroll
  for (int i = 0; i < 2; ++i) {
    int p = tid + i * 256;
    int row = p >> 2, c = (p & 3) ^ (row & 3);
    srcA[i] = A + (size_t)(m0 + row) * K + c * 8;
    dstA[i] = p * 8;
    srcB[i] = BT + (size_t)(n0 + row) * K + c * 8;
    dstB[i] = 4096 + p * 8;
  }

  f32x4 acc[4][4];
  #pragma unroll
  for (int i = 0; i < 4; ++i)
    #pragma unroll
    for (int j = 0; j < 4; ++j) acc[i][j] = (f32x4){0.f, 0.f, 0.f, 0.f};

  auto stage = [&](int bsel) {     // 4 dma16/thread = one full K-tile
    u16* buf = &lds[bsel * 8192];
    #pragma unroll
    for (int i = 0; i < 2; ++i) {
      dma16(srcA[i], buf + dstA[i]); srcA[i] += 32;
      dma16(srcB[i], buf + dstB[i]); srcB[i] += 32;
    }
  };

  stage(0); stage(1); stage(2);    // 12 loads/thread in flight (3 K-tiles)

  const int NT = K >> 5;
  int bsel = 0;
  const int xc = lm & 3;
  for (int tI = 0; tI < NT; ++tI) {
    // tile tI's 4 loads are the oldest; allow 2 newer tiles in flight
    if (tI + 2 < NT)      asm volatile("s_waitcnt vmcnt(8)" ::: "memory");
    else if (tI + 1 < NT) asm volatile("s_waitcnt vmcnt(4)" ::: "memory");
    else                  asm volatile("s_waitcnt vmcnt(0)" ::: "memory");
    asm volatile("s_barrier" ::: "memory");   // raw: no vmcnt(0) drain

    const u16* Ab = &lds[bsel * 8192];
    const u16* Bb = Ab + 4096;
    const int ch = (quad ^ xc) * 8;
    bf16x8 a[4], b[4];
    #pragma unroll
    for (int i = 0; i < 4; ++i)
      a[i] = *(const bf16x8*)&Ab[(wm * 64 + i * 16 + lm) * 32 + ch];
    #pragma unroll
    for (int j = 0; j < 4; ++j)
      b[j] = *(const bf16x8*)&Bb[(wn * 64 + j * 16 + lm) * 32 + ch];
    __builtin_amdgcn_s_setprio(1);
    #pragma unroll
    for (int i = 0; i < 4; ++i)
      #pragma unroll
      for (int j = 0; j < 4; ++j)
        acc[i][j] = __builtin_amdgcn_mfma_f32_16x16x32_bf16(a[i], b[j], acc[i][j], 0, 0, 0);
    __builtin_amdgcn_s_setprio(0);
    asm volatile("s_barrier" ::: "memory");   // all waves done reading buf bsel
    if (tI + 3 < NT) stage(bsel);             // overwrite just-freed buffer
    bsel = (bsel == 2) ? 0 : bsel + 1;
  }

  #pragma unroll
  for (int i = 0; i < 4; ++i) {
    #pragma unroll
    for (int r = 0; r < 4; ++r) {
      size_t gr = (size_t)(m0 + wm * 64 + i * 16 + quad * 4 + r);
      #pragma unroll
      for (int j = 0; j < 4; ++j) {
        int gc = n0 + wn * 64 + j * 16 + lm;
        if (OUT_BF16) ((u16*)Cv)[gr * N + gc] = f2bf(acc[i][j][r]);
        else          ((float*)Cv)[gr * N + gc] = acc[i][j][r];
      }
    }
  }
}

// ---------------- RoPE on K columns only (Q is roped inside attn) ----------
__global__ __launch_bounds__(256) void rope2k(u16* p) {
  const int row = blockIdx.x;
  const int pos = row & (TT - 1);
  u16* base = p + (size_t)row * NKV + 2048;
  const int kh = threadIdx.x >> 6, f = threadIdx.x & 63;
  const int col = kh * 128;
  u32 u = *(const u32*)(base + col + 2 * f);
  float e0 = bf2f(u & 0xffffu);
  float e1 = bf2f(u >> 16);
  __syncthreads();   // all pair-reads done before any write (layout permutes)
  float inv = exp2f((float)f * -0.20762050593046898f);  // 10000^(-f/64)
  float ang = (float)pos * inv;
  float sn, cs;
  fast_sincos(ang, &sn, &cs);
  base[col + f]      = f2bf(e0 * cs - e1 * sn);
  base[col + 64 + f] = f2bf(e0 * sn + e1 * cs);
}

// ---------------- V transpose: QKV v-part -> Vt[(b*4+vh)*128+d][T] ---------
__global__ __launch_bounds__(256) void vtrans(const u16* __restrict__ QKV,
                                              u16* __restrict__ Vt) {
  __shared__ u16 tl[64][72];
  const int t0 = blockIdx.x * 64;
  const int y  = blockIdx.y;        // 0..7
  const int b  = blockIdx.z;
  #pragma unroll
  for (int i = 0; i < 2; ++i) {
    int idx = threadIdx.x + i * 256;
    int r = idx >> 3, c = (idx & 7) * 8;
    *(uint4*)&tl[r][c] =
        *(const uint4*)(QKV + (size_t)(b * TT + t0 + r) * NKV + 2560 + y * 64 + c);
  }
  __syncthreads();
  const int vh = y >> 1;
  #pragma unroll
  for (int i = 0; i < 2; ++i) {
    int idx = threadIdx.x + i * 256;
    int dr = idx >> 3, tc = (idx & 7) * 8;
    u16 tmp[8];
    #pragma unroll
    for (int j = 0; j < 8; ++j) tmp[j] = tl[tc + j][dr];
    int dloc = (y & 1) * 64 + dr;
    *(uint4*)(Vt + (size_t)((b * KVHN + vh) * HDIM + dloc) * TT + t0 + tc) =
        *(const uint4*)tmp;
  }
}

// ---------------- MFMA flash attention v4 + fused Q-RoPE (HW trig) ---------
// R9 version verbatim (PASSED, 101.7us).
__global__ __launch_bounds__(256, 4) void attn4(const u16* __restrict__ QKV,
                                                const u16* __restrict__ Vt,
                                                u16* __restrict__ Ob) {
  __shared__ u16 KsA[32 * 128], KsB[32 * 128];
  __shared__ u16 VsA[64 * 64], VsB[64 * 64];
  __shared__ u16 Pw[4 * 512];
  const int t = threadIdx.x;
  const int l = t & 63, w = t >> 6;
  const int lm = l & 15, quad = l >> 4;
  const int h = blockIdx.y, b = blockIdx.z;
  const int qbase = (blockIdx.x + (blockIdx.y & 7)) & 31;
  const int qt = (blockIdx.y & 8) ? (31 - qbase) : qbase;
  const int kvh = h >> 2;
  const int q0 = qt * 64;
  const int last = 2 * qt + 1;
  const int wu = __builtin_amdgcn_readfirstlane(w);
  u16* pwv = &Pw[w * 512];
  constexpr float L2E = 1.4426950408889634f;

  f32x4 o[8];
  #pragma unroll
  for (int i = 0; i < 8; ++i) o[i] = (f32x4){0.f, 0.f, 0.f, 0.f};
  float m_ = -1e30f, l_ = 0.f;

  const u16 *kg[2], *vg[2];
  int koff[2], voff[2];
  #pragma unroll
  for (int i = 0; i < 2; ++i) {
    int p0 = (wu * 2 + i) * 64, p = p0 + l;
    int krow = p >> 4, kcp = p & 15, kcl = kcp ^ (krow & 15);
    kg[i] = QKV + (size_t)(b * TT + krow) * NKV + 2048 + kvh * HDIM + kcl * 8;
    koff[i] = p0 * 8;
    int vrow = p >> 3, vphys = p & 7, vcl = vphys ^ (vrow & 7);
    int vd = vrow + (vcl >> 2) * 64, vtch = vcl & 3;
    vg[i] = Vt + (size_t)((b * KVHN + kvh) * HDIM + vd) * TT + vtch * 8;
    voff[i] = p0 * 8;
  }

  #pragma unroll
  for (int i = 0; i < 2; ++i) {
    dma16(kg[i], KsA + koff[i]);
    dma16(vg[i], VsA + voff[i]);
    kg[i] += 32 * NKV;
    vg[i] += 32;
  }

  const int qrow = q0 + w * 16 + lm;

  // Q fragments with fused RoPE + scale (hidden under tile-0 staging)
  bf16x8 qf[4];
  {
    const u16* qp = QKV + (size_t)(b * TT + qrow) * NKV + h * HDIM;
    bf16x8 raw[4];   // [kp][half]: raw pairs at kp*64 + quad*16 + half*8
    #pragma unroll
    for (int i = 0; i < 4; ++i)
      raw[i] = *(const bf16x8*)(qp + (i >> 1) * 64 + quad * 16 + (i & 1) * 8);
    #pragma unroll
    for (int kp = 0; kp < 2; ++kp)
      #pragma unroll
      for (int e = 0; e < 8; ++e) {
        int f = kp * 32 + quad * 8 + e;
        float ang = (float)qrow * exp2f((float)f * -0.20762050593046898f);
        float sn, cs;
        fast_sincos(ang, &sn, &cs);
        float e0 = (float)raw[kp * 2 + (e >> 2)][(2 * e) & 7];
        float e1 = (float)raw[kp * 2 + (e >> 2)][(2 * e + 1) & 7];
        qf[kp][e]     = (__bf16)((e0 * cs - e1 * sn) * 0.08838834764831845f);
        qf[kp + 2][e] = (__bf16)((e0 * sn + e1 * cs) * 0.08838834764831845f);
      }
  }

  auto body = [&](int kt, const u16* kcur, const u16* vcur, u16* knx, u16* vnx) {
    __syncthreads();
    const bool pf = kt < last;
    if (pf) {
      #pragma unroll
      for (int i = 0; i < 2; ++i) dma16(vg[i], vnx + voff[i]);
    }

    f32x4 s[2];
    s[0] = (f32x4){0.f, 0.f, 0.f, 0.f};
    s[1] = (f32x4){0.f, 0.f, 0.f, 0.f};
    __builtin_amdgcn_s_setprio(1);
    #pragma unroll
    for (int ks = 0; ks < 4; ++ks) {
      #pragma unroll
      for (int mt = 0; mt < 2; ++mt) {
        bf16x8 kb = *(const bf16x8*)&kcur[(mt * 16 + lm) * 128 + (((ks * 4 + quad) ^ lm) * 8)];
        s[mt] = __builtin_amdgcn_mfma_f32_16x16x32_bf16(kb, qf[ks], s[mt], 0, 0, 0);
      }
    }
    __builtin_amdgcn_s_setprio(0);
    if (pf) {
      #pragma unroll
      for (int i = 0; i < 2; ++i) {
        dma16(kg[i], knx + koff[i]);
        kg[i] += 32 * NKV;
        vg[i] += 32;
      }
    }

    if (kt >= 2 * qt) {
      #pragma unroll
      for (int mt = 0; mt < 2; ++mt)
        #pragma unroll
        for (int r = 0; r < 4; ++r) {
          int kv = kt * 32 + mt * 16 + quad * 4 + r;
          if (kv > qrow) s[mt][r] = -1e30f;
        }
    }

    float mx = -1e30f;
    #pragma unroll
    for (int mt = 0; mt < 2; ++mt)
      #pragma unroll
      for (int r = 0; r < 4; ++r) mx = fmaxf(mx, s[mt][r]);
    mx = fmaxf(mx, __shfl_xor(mx, 16));
    mx = fmaxf(mx, __shfl_xor(mx, 32));
    bool upd = mx > m_ + 8.f;
    float mn = upd ? mx : m_;
    float al = upd ? exp2f((m_ - mn) * L2E) : 1.f;
    m_ = mn;
    float sum = 0.f;
    #pragma unroll
    for (int mt = 0; mt < 2; ++mt)
      #pragma unroll
      for (int r = 0; r < 4; ++r) {
        float pv = exp2f((s[mt][r] - mn) * L2E);
        s[mt][r] = pv;
        sum += pv;
      }
    sum += __shfl_xor(sum, 16);
    sum += __shfl_xor(sum, 32);
    l_ = l_ * al + sum;

    #pragma unroll
    for (int mt = 0; mt < 2; ++mt) {
      u32 p01 = pack2(s[mt][0], s[mt][1]);
      u32 p23 = pack2(s[mt][2], s[mt][3]);
      int c = mt * 2 + (quad >> 1);
      int addr = (lm >> 1) * 64 + ((lm & 1) * 4 + (c ^ ((lm >> 1) & 3))) * 8 + (quad & 1) * 4;
      uint2 uv; uv.x = p01; uv.y = p23;
      *(uint2*)&pwv[addr] = uv;
    }
    if (__any(upd)) {
      #pragma unroll
      for (int i = 0; i < 8; ++i)
        #pragma unroll
        for (int r = 0; r < 4; ++r) o[i][r] *= al;
    }

    int paddr = (lm >> 1) * 64 + ((lm & 1) * 4 + (quad ^ ((lm >> 1) & 3))) * 8;
    bf16x8 pb = *(const bf16x8*)&pwv[paddr];
    __builtin_amdgcn_s_setprio(1);
    #pragma unroll
    for (int mt2 = 0; mt2 < 8; ++mt2) {
      int vrow = (mt2 & 3) * 16 + lm;
      int vphys = ((mt2 >> 2) * 4 + quad) ^ (vrow & 7);
      bf16x8 vb = *(const bf16x8*)&vcur[vrow * 64 + vphys * 8];
      o[mt2] = __builtin_amdgcn_mfma_f32_16x16x32_bf16(vb, pb, o[mt2], 0, 0, 0);
    }
    __builtin_amdgcn_s_setprio(0);
  };

  for (int kt = 0; kt <= last; ++kt) {
    if ((kt & 1) == 0) body(kt, KsA, VsA, KsB, VsB);
    else               body(kt, KsB, VsB, KsA, VsA);
  }

  __syncthreads();
  u16* esc = ((w & 2) ? KsB : KsA) + (w & 1) * 2048;
  float inv = 1.f / l_;
  #pragma unroll
  for (int mt2 = 0; mt2 < 8; ++mt2) {
    u32 a0 = pack2(o[mt2][0] * inv, o[mt2][1] * inv);
    u32 a1 = pack2(o[mt2][2] * inv, o[mt2][3] * inv);
    int phys = (mt2 * 2 + (quad >> 1)) ^ (lm & 7);
    int addr = lm * 128 + phys * 8 + (quad & 1) * 4;
    uint2 uv; uv.x = a0; uv.y = a1;
    *(uint2*)&esc[addr] = uv;
  }
  #pragma unroll
  for (int i = 0; i < 4; ++i) {
    int p = i * 64 + l;
    int row = p >> 4, cl = p & 15;
    int cph = cl ^ (row & 7);
    uint4 val = *(const uint4*)&esc[row * 128 + cph * 8];
    *(uint4*)(Ob + (size_t)(b * TT + q0 + w * 16 + row) * DD + h * HDIM + cl * 8) = val;
  }
}

extern "C" void kernel_launch(void* const* d_in, const int* in_sizes, int n_in,
                              void* d_out, int out_size, void* d_ws, size_t ws_size,
                              hipStream_t stream) {
  const float* x  = (const float*)d_in[0];
  const float* Wq = (const float*)d_in[1];
  const float* Wk = (const float*)d_in[2];
  const float* Wv = (const float*)d_in[3];
  const float* Wo = (const float*)d_in[4];
  float* out = (float*)d_out;

  // ws (u16 elems): xb @0 (8M, -> Ob) | WqkvT @8M (6M, -> Vt) | WoT @14.68M (4M)
  u16* xb    = (u16*)d_ws;
  u16* WqkvT = xb + 8388608;
  u16* WoT   = xb + 14680064;
  u16* Vt    = WqkvT;               // alias, live after QKV GEMM
  u16* Ob    = xb;                  // alias, live after QKV GEMM
  u16* QKVb  = (u16*)d_out;         // bf16 [4096][3072] in the 32MB out buffer

  dim3 blk(256);
  castf2b<<<8192, blk, 0, stream>>>(x, xb);
  tcast<<<dim3(64, 64), blk, 0, stream>>>(Wq, WqkvT, DD, DD);
  tcast<<<dim3(16, 64), blk, 0, stream>>>(Wk, WqkvT + (size_t)2048 * DD, DD, 512);
  tcast<<<dim3(16, 64), blk, 0, stream>>>(Wv, WqkvT + (size_t)2560 * DD, DD, 512);
  tcast<<<dim3(64, 64), blk, 0, stream>>>(Wo, WoT, DD, DD);

  gemmt<1><<<dim3(NKV / 128, 32), blk, 0, stream>>>(xb, WqkvT, QKVb, NKV, DD);
  rope2k<<<BB * TT, blk, 0, stream>>>(QKVb);
  vtrans<<<dim3(32, 8, BB), blk, 0, stream>>>(QKVb, Vt);
  attn4<<<dim3(32, HH, BB), blk, 0, stream>>>(QKVb, Vt, Ob);
  gemmt<0><<<dim3(DD / 128, 32), blk, 0, stream>>>(Ob, WoT, out, DD, DD);
}

// Round 11
// 311.933 us; speedup vs baseline: 1.0261x; 1.0261x over previous
//
#include <hip/hip_runtime.h>
#include <math.h>

#define BB 2
#define TT 2048
#define DD 2048
#define HH 16
#define KVHN 4
#define HDIM 128
#define NKV 3072   // packed q|k|v row width

typedef unsigned short u16;
typedef unsigned int u32;
typedef __bf16 bf16x8 __attribute__((ext_vector_type(8)));
typedef float  f32x4  __attribute__((ext_vector_type(4)));

#define AS1 __attribute__((address_space(1)))
#define AS3 __attribute__((address_space(3)))

__device__ __forceinline__ void dma16(const u16* g, u16* l) {
  __builtin_amdgcn_global_load_lds((const AS1 u32*)g, (AS3 u32*)l, 16, 0, 0);
}

__device__ __forceinline__ u16 f2bf(float f) {
  u32 u = __float_as_uint(f);
  u32 r = (u + 0x7FFFu + ((u >> 16) & 1u)) >> 16;
  return (u16)r;
}
__device__ __forceinline__ float bf2f(u32 h) { return __uint_as_float(h << 16); }

__device__ __forceinline__ u32 pack2(float a, float b) {
  union { __bf16 h[2]; u32 u; } cv;
  cv.h[0] = (__bf16)a; cv.h[1] = (__bf16)b;
  return cv.u;
}

// HW trig: reduce to revolutions, v_sin/v_cos (D = sin(S0 * 2pi)).
__device__ __forceinline__ void fast_sincos(float ang, float* sn, float* cs) {
  float rev = ang * 0.15915494309189535f;   // ang / 2pi
  rev -= floorf(rev);                        // [0, 1)
  float s, c;
  asm volatile("v_sin_f32 %0, %1" : "=v"(s) : "v"(rev));
  asm volatile("v_cos_f32 %0, %1" : "=v"(c) : "v"(rev));
  *sn = s; *cs = c;
}

// ---------------- cast fp32 -> bf16 ----------------------------------------
__global__ __launch_bounds__(256) void castf2b(const float* __restrict__ in,
                                               u16* __restrict__ out) {
  size_t i4 = (size_t)blockIdx.x * 256 + threadIdx.x;
  float4 v = *(const float4*)(in + i4 * 4);
  ushort4 o;
  o.x = f2bf(v.x); o.y = f2bf(v.y); o.z = f2bf(v.z); o.w = f2bf(v.w);
  *(ushort4*)(out + i4 * 4) = o;
}

// ---------------- transpose + cast: W[K][N] fp32 -> WT[N][K] bf16 ----------
__global__ __launch_bounds__(256) void tcast(const float* __restrict__ W,
                                             u16* __restrict__ WT,
                                             int K, int N) {
  __shared__ float tile[32][33];
  const int n0 = blockIdx.x * 32, k0 = blockIdx.y * 32;
  const int r = threadIdx.x >> 3;
  const int c4 = (threadIdx.x & 7) * 4;
  float4 v = *(const float4*)(W + (size_t)(k0 + r) * N + n0 + c4);
  tile[r][c4 + 0] = v.x; tile[r][c4 + 1] = v.y;
  tile[r][c4 + 2] = v.z; tile[r][c4 + 3] = v.w;
  __syncthreads();
  ushort4 o;
  o.x = f2bf(tile[c4 + 0][r]); o.y = f2bf(tile[c4 + 1][r]);
  o.z = f2bf(tile[c4 + 2][r]); o.w = f2bf(tile[c4 + 3][r]);
  *(ushort4*)(WT + (size_t)(n0 + r) * K + k0 + c4) = o;
}

// ---------------- counted-vmcnt MFMA GEMM, 128x128 / 4-wave / tri-buffer ---
// R10 structure (PASSED) with ONE change: XOR mask (row&3) -> (row^(row>>2))&3.
// Old mask left rows {lm, lm+4, lm+8, lm+12} on the same bank with the same
// swizzle -> 4-way ds_read conflict (1.58x, m136).  New mask distinguishes
// them; for read rows (wm*64+i*16+lm) it collapses to lane-constant
// (lm^(lm>>2))&3.  Involution applied to pre-swizzled GLOBAL source and
// ds_read chunk (both-sides rule) -> value-identical layout permutation.
template <int OUT_BF16>
__global__ __launch_bounds__(256, 3) void gemmt(const u16* __restrict__ A,
                                                const u16* __restrict__ BT,
                                                void* __restrict__ Cv,
                                                int N, int K) {
  __shared__ u16 lds[3 * 8192];    // per buffer: A 128x32 (4096) | B 128x32 (4096)
  const int t = threadIdx.x;
  const int l = t & 63, w = t >> 6;
  const int lm = l & 15, quad = l >> 4;
  const int wm = w & 1, wn = w >> 1;
  // XCD swizzle (bijective: nwg % 8 == 0 for both grids: 768, 512)
  const int Nx = gridDim.x;
  const int nwg = Nx * gridDim.y;
  const int flat = blockIdx.y * Nx + blockIdx.x;
  const int cpx = nwg >> 3;
  const int swz = (flat & 7) * cpx + (flat >> 3);
  const int m0 = (swz / Nx) * 128, n0 = (swz % Nx) * 128;
  const int wu = __builtin_amdgcn_readfirstlane(w);
  const int tid = wu * 64 + l;

  // staging source pointers (pre-swizzled global col) + uniform LDS dests
  const u16* srcA[2]; int dstA[2];
  const u16* srcB[2]; int dstB[2];
  #pragma unroll
  for (int i = 0; i < 2; ++i) {
    int p = tid + i * 256;
    int row = p >> 2, c = (p & 3) ^ ((row ^ (row >> 2)) & 3);
    srcA[i] = A + (size_t)(m0 + row) * K + c * 8;
    dstA[i] = p * 8;
    srcB[i] = BT + (size_t)(n0 + row) * K + c * 8;
    dstB[i] = 4096 + p * 8;
  }

  f32x4 acc[4][4];
  #pragma unroll
  for (int i = 0; i < 4; ++i)
    #pragma unroll
    for (int j = 0; j < 4; ++j) acc[i][j] = (f32x4){0.f, 0.f, 0.f, 0.f};

  auto stage = [&](int bsel) {     // 4 dma16/thread = one full K-tile
    u16* buf = &lds[bsel * 8192];
    #pragma unroll
    for (int i = 0; i < 2; ++i) {
      dma16(srcA[i], buf + dstA[i]); srcA[i] += 32;
      dma16(srcB[i], buf + dstB[i]); srcB[i] += 32;
    }
  };

  stage(0); stage(1); stage(2);    // 12 loads/thread in flight (3 K-tiles)

  const int NT = K >> 5;
  int bsel = 0;
  const int xc = (lm ^ (lm >> 2)) & 3;
  for (int tI = 0; tI < NT; ++tI) {
    // tile tI's 4 loads are the oldest; allow 2 newer tiles in flight
    if (tI + 2 < NT)      asm volatile("s_waitcnt vmcnt(8)" ::: "memory");
    else if (tI + 1 < NT) asm volatile("s_waitcnt vmcnt(4)" ::: "memory");
    else                  asm volatile("s_waitcnt vmcnt(0)" ::: "memory");
    asm volatile("s_barrier" ::: "memory");   // raw: no vmcnt(0) drain

    const u16* Ab = &lds[bsel * 8192];
    const u16* Bb = Ab + 4096;
    const int ch = (quad ^ xc) * 8;
    bf16x8 a[4], b[4];
    #pragma unroll
    for (int i = 0; i < 4; ++i)
      a[i] = *(const bf16x8*)&Ab[(wm * 64 + i * 16 + lm) * 32 + ch];
    #pragma unroll
    for (int j = 0; j < 4; ++j)
      b[j] = *(const bf16x8*)&Bb[(wn * 64 + j * 16 + lm) * 32 + ch];
    __builtin_amdgcn_s_setprio(1);
    #pragma unroll
    for (int i = 0; i < 4; ++i)
      #pragma unroll
      for (int j = 0; j < 4; ++j)
        acc[i][j] = __builtin_amdgcn_mfma_f32_16x16x32_bf16(a[i], b[j], acc[i][j], 0, 0, 0);
    __builtin_amdgcn_s_setprio(0);
    asm volatile("s_barrier" ::: "memory");   // all waves done reading buf bsel
    if (tI + 3 < NT) stage(bsel);             // overwrite just-freed buffer
    bsel = (bsel == 2) ? 0 : bsel + 1;
  }

  #pragma unroll
  for (int i = 0; i < 4; ++i) {
    #pragma unroll
    for (int r = 0; r < 4; ++r) {
      size_t gr = (size_t)(m0 + wm * 64 + i * 16 + quad * 4 + r);
      #pragma unroll
      for (int j = 0; j < 4; ++j) {
        int gc = n0 + wn * 64 + j * 16 + lm;
        if (OUT_BF16) ((u16*)Cv)[gr * N + gc] = f2bf(acc[i][j][r]);
        else          ((float*)Cv)[gr * N + gc] = acc[i][j][r];
      }
    }
  }
}

// ---------------- RoPE on K columns only (Q is roped inside attn) ----------
__global__ __launch_bounds__(256) void rope2k(u16* p) {
  const int row = blockIdx.x;
  const int pos = row & (TT - 1);
  u16* base = p + (size_t)row * NKV + 2048;
  const int kh = threadIdx.x >> 6, f = threadIdx.x & 63;
  const int col = kh * 128;
  u32 u = *(const u32*)(base + col + 2 * f);
  float e0 = bf2f(u & 0xffffu);
  float e1 = bf2f(u >> 16);
  __syncthreads();   // all pair-reads done before any write (layout permutes)
  float inv = exp2f((float)f * -0.20762050593046898f);  // 10000^(-f/64)
  float ang = (float)pos * inv;
  float sn, cs;
  fast_sincos(ang, &sn, &cs);
  base[col + f]      = f2bf(e0 * cs - e1 * sn);
  base[col + 64 + f] = f2bf(e0 * sn + e1 * cs);
}

// ---------------- V transpose: QKV v-part -> Vt[(b*4+vh)*128+d][T] ---------
__global__ __launch_bounds__(256) void vtrans(const u16* __restrict__ QKV,
                                              u16* __restrict__ Vt) {
  __shared__ u16 tl[64][72];
  const int t0 = blockIdx.x * 64;
  const int y  = blockIdx.y;        // 0..7
  const int b  = blockIdx.z;
  #pragma unroll
  for (int i = 0; i < 2; ++i) {
    int idx = threadIdx.x + i * 256;
    int r = idx >> 3, c = (idx & 7) * 8;
    *(uint4*)&tl[r][c] =
        *(const uint4*)(QKV + (size_t)(b * TT + t0 + r) * NKV + 2560 + y * 64 + c);
  }
  __syncthreads();
  const int vh = y >> 1;
  #pragma unroll
  for (int i = 0; i < 2; ++i) {
    int idx = threadIdx.x + i * 256;
    int dr = idx >> 3, tc = (idx & 7) * 8;
    u16 tmp[8];
    #pragma unroll
    for (int j = 0; j < 8; ++j) tmp[j] = tl[tc + j][dr];
    int dloc = (y & 1) * 64 + dr;
    *(uint4*)(Vt + (size_t)((b * KVHN + vh) * HDIM + dloc) * TT + t0 + tc) =
        *(const uint4*)tmp;
  }
}

// ---------------- MFMA flash attention v4 + fused Q-RoPE (HW trig) ---------
// R10 body with two serial-chain cuts:
//  (1) deferred row-sum: l_ kept as per-lane partial, reduced once in the
//      epilogue (exact: al is row-uniform, linearity) -> -2 shfl/body.
//  (2) max-reduce shfls only when __any(own_max > m_+8) -- trigger is exactly
//      the old row condition (row-max = max of own-maxes), wave-OR is merely
//      conservative (al=1 rows unaffected) -> -2 shfl/body common path.
__global__ __launch_bounds__(256, 4) void attn4(const u16* __restrict__ QKV,
                                                const u16* __restrict__ Vt,
                                                u16* __restrict__ Ob) {
  __shared__ u16 KsA[32 * 128], KsB[32 * 128];
  __shared__ u16 VsA[64 * 64], VsB[64 * 64];
  __shared__ u16 Pw[4 * 512];
  const int t = threadIdx.x;
  const int l = t & 63, w = t >> 6;
  const int lm = l & 15, quad = l >> 4;
  const int h = blockIdx.y, b = blockIdx.z;
  const int qbase = (blockIdx.x + (blockIdx.y & 7)) & 31;
  const int qt = (blockIdx.y & 8) ? (31 - qbase) : qbase;
  const int kvh = h >> 2;
  const int q0 = qt * 64;
  const int last = 2 * qt + 1;
  const int wu = __builtin_amdgcn_readfirstlane(w);
  u16* pwv = &Pw[w * 512];
  constexpr float L2E = 1.4426950408889634f;

  f32x4 o[8];
  #pragma unroll
  for (int i = 0; i < 8; ++i) o[i] = (f32x4){0.f, 0.f, 0.f, 0.f};
  float m_ = -1e30f, l_ = 0.f;

  const u16 *kg[2], *vg[2];
  int koff[2], voff[2];
  #pragma unroll
  for (int i = 0; i < 2; ++i) {
    int p0 = (wu * 2 + i) * 64, p = p0 + l;
    int krow = p >> 4, kcp = p & 15, kcl = kcp ^ (krow & 15);
    kg[i] = QKV + (size_t)(b * TT + krow) * NKV + 2048 + kvh * HDIM + kcl * 8;
    koff[i] = p0 * 8;
    int vrow = p >> 3, vphys = p & 7, vcl = vphys ^ (vrow & 7);
    int vd = vrow + (vcl >> 2) * 64, vtch = vcl & 3;
    vg[i] = Vt + (size_t)((b * KVHN + kvh) * HDIM + vd) * TT + vtch * 8;
    voff[i] = p0 * 8;
  }

  #pragma unroll
  for (int i = 0; i < 2; ++i) {
    dma16(kg[i], KsA + koff[i]);
    dma16(vg[i], VsA + voff[i]);
    kg[i] += 32 * NKV;
    vg[i] += 32;
  }

  const int qrow = q0 + w * 16 + lm;

  // Q fragments with fused RoPE + scale (hidden under tile-0 staging)
  bf16x8 qf[4];
  {
    const u16* qp = QKV + (size_t)(b * TT + qrow) * NKV + h * HDIM;
    bf16x8 raw[4];   // [kp][half]: raw pairs at kp*64 + quad*16 + half*8
    #pragma unroll
    for (int i = 0; i < 4; ++i)
      raw[i] = *(const bf16x8*)(qp + (i >> 1) * 64 + quad * 16 + (i & 1) * 8);
    #pragma unroll
    for (int kp = 0; kp < 2; ++kp)
      #pragma unroll
      for (int e = 0; e < 8; ++e) {
        int f = kp * 32 + quad * 8 + e;
        float ang = (float)qrow * exp2f((float)f * -0.20762050593046898f);
        float sn, cs;
        fast_sincos(ang, &sn, &cs);
        float e0 = (float)raw[kp * 2 + (e >> 2)][(2 * e) & 7];
        float e1 = (float)raw[kp * 2 + (e >> 2)][(2 * e + 1) & 7];
        qf[kp][e]     = (__bf16)((e0 * cs - e1 * sn) * 0.08838834764831845f);
        qf[kp + 2][e] = (__bf16)((e0 * sn + e1 * cs) * 0.08838834764831845f);
      }
  }

  auto body = [&](int kt, const u16* kcur, const u16* vcur, u16* knx, u16* vnx) {
    __syncthreads();
    const bool pf = kt < last;
    if (pf) {
      #pragma unroll
      for (int i = 0; i < 2; ++i) dma16(vg[i], vnx + voff[i]);
    }

    f32x4 s[2];
    s[0] = (f32x4){0.f, 0.f, 0.f, 0.f};
    s[1] = (f32x4){0.f, 0.f, 0.f, 0.f};
    __builtin_amdgcn_s_setprio(1);
    #pragma unroll
    for (int ks = 0; ks < 4; ++ks) {
      #pragma unroll
      for (int mt = 0; mt < 2; ++mt) {
        bf16x8 kb = *(const bf16x8*)&kcur[(mt * 16 + lm) * 128 + (((ks * 4 + quad) ^ lm) * 8)];
        s[mt] = __builtin_amdgcn_mfma_f32_16x16x32_bf16(kb, qf[ks], s[mt], 0, 0, 0);
      }
    }
    __builtin_amdgcn_s_setprio(0);
    if (pf) {
      #pragma unroll
      for (int i = 0; i < 2; ++i) {
        dma16(kg[i], knx + koff[i]);
        kg[i] += 32 * NKV;
        vg[i] += 32;
      }
    }

    if (kt >= 2 * qt) {
      #pragma unroll
      for (int mt = 0; mt < 2; ++mt)
        #pragma unroll
        for (int r = 0; r < 4; ++r) {
          int kv = kt * 32 + mt * 16 + quad * 4 + r;
          if (kv > qrow) s[mt][r] = -1e30f;
        }
    }

    // own-lane max over 8 values; cross-quad reduce ONLY when needed
    float mx = -1e30f;
    #pragma unroll
    for (int mt = 0; mt < 2; ++mt)
      #pragma unroll
      for (int r = 0; r < 4; ++r) mx = fmaxf(mx, s[mt][r]);
    bool anyupd = __any(mx > m_ + 8.f);
    float al = 1.f;
    if (anyupd) {
      float rmx = fmaxf(mx, __shfl_xor(mx, 16));
      rmx = fmaxf(rmx, __shfl_xor(rmx, 32));
      float mn = fmaxf(m_, rmx);
      al = exp2f((m_ - mn) * L2E);
      m_ = mn;
    }
    float sum = 0.f;
    #pragma unroll
    for (int mt = 0; mt < 2; ++mt)
      #pragma unroll
      for (int r = 0; r < 4; ++r) {
        float pv = exp2f((s[mt][r] - m_) * L2E);
        s[mt][r] = pv;
        sum += pv;
      }
    l_ = l_ * al + sum;   // per-lane partial; reduced once in epilogue

    #pragma unroll
    for (int mt = 0; mt < 2; ++mt) {
      u32 p01 = pack2(s[mt][0], s[mt][1]);
      u32 p23 = pack2(s[mt][2], s[mt][3]);
      int c = mt * 2 + (quad >> 1);
      int addr = (lm >> 1) * 64 + ((lm & 1) * 4 + (c ^ ((lm >> 1) & 3))) * 8 + (quad & 1) * 4;
      uint2 uv; uv.x = p01; uv.y = p23;
      *(uint2*)&pwv[addr] = uv;
    }
    if (anyupd) {
      #pragma unroll
      for (int i = 0; i < 8; ++i)
        #pragma unroll
        for (int r = 0; r < 4; ++r) o[i][r] *= al;
    }

    int paddr = (lm >> 1) * 64 + ((lm & 1) * 4 + (quad ^ ((lm >> 1) & 3))) * 8;
    bf16x8 pb = *(const bf16x8*)&pwv[paddr];
    __builtin_amdgcn_s_setprio(1);
    #pragma unroll
    for (int mt2 = 0; mt2 < 8; ++mt2) {
      int vrow = (mt2 & 3) * 16 + lm;
      int vphys = ((mt2 >> 2) * 4 + quad) ^ (vrow & 7);
      bf16x8 vb = *(const bf16x8*)&vcur[vrow * 64 + vphys * 8];
      o[mt2] = __builtin_amdgcn_mfma_f32_16x16x32_bf16(vb, pb, o[mt2], 0, 0, 0);
    }
    __builtin_amdgcn_s_setprio(0);
  };

  for (int kt = 0; kt <= last; ++kt) {
    if ((kt & 1) == 0) body(kt, KsA, VsA, KsB, VsB);
    else               body(kt, KsB, VsB, KsA, VsA);
  }

  // epilogue: reduce the deferred per-lane row-sum, then normalize + store
  l_ += __shfl_xor(l_, 16);
  l_ += __shfl_xor(l_, 32);
  __syncthreads();
  u16* esc = ((w & 2) ? KsB : KsA) + (w & 1) * 2048;
  float inv = 1.f / l_;
  #pragma unroll
  for (int mt2 = 0; mt2 < 8; ++mt2) {
    u32 a0 = pack2(o[mt2][0] * inv, o[mt2][1] * inv);
    u32 a1 = pack2(o[mt2][2] * inv, o[mt2][3] * inv);
    int phys = (mt2 * 2 + (quad >> 1)) ^ (lm & 7);
    int addr = lm * 128 + phys * 8 + (quad & 1) * 4;
    uint2 uv; uv.x = a0; uv.y = a1;
    *(uint2*)&esc[addr] = uv;
  }
  #pragma unroll
  for (int i = 0; i < 4; ++i) {
    int p = i * 64 + l;
    int row = p >> 4, cl = p & 15;
    int cph = cl ^ (row & 7);
    uint4 val = *(const uint4*)&esc[row * 128 + cph * 8];
    *(uint4*)(Ob + (size_t)(b * TT + q0 + w * 16 + row) * DD + h * HDIM + cl * 8) = val;
  }
}

extern "C" void kernel_launch(void* const* d_in, const int* in_sizes, int n_in,
                              void* d_out, int out_size, void* d_ws, size_t ws_size,
                              hipStream_t stream) {
  const float* x  = (const float*)d_in[0];
  const float* Wq = (const float*)d_in[1];
  const float* Wk = (const float*)d_in[2];
  const float* Wv = (const float*)d_in[3];
  const float* Wo = (const float*)d_in[4];
  float* out = (float*)d_out;

  // ws (u16 elems): xb @0 (8M, -> Ob) | WqkvT @8M (6M, -> Vt) | WoT @14.68M (4M)
  u16* xb    = (u16*)d_ws;
  u16* WqkvT = xb + 8388608;
  u16* WoT   = xb + 14680064;
  u16* Vt    = WqkvT;               // alias, live after QKV GEMM
  u16* Ob    = xb;                  // alias, live after QKV GEMM
  u16* QKVb  = (u16*)d_out;         // bf16 [4096][3072] in the 32MB out buffer

  dim3 blk(256);
  castf2b<<<8192, blk, 0, stream>>>(x, xb);
  tcast<<<dim3(64, 64), blk, 0, stream>>>(Wq, WqkvT, DD, DD);
  tcast<<<dim3(16, 64), blk, 0, stream>>>(Wk, WqkvT + (size_t)2048 * DD, DD, 512);
  tcast<<<dim3(16, 64), blk, 0, stream>>>(Wv, WqkvT + (size_t)2560 * DD, DD, 512);
  tcast<<<dim3(64, 64), blk, 0, stream>>>(Wo, WoT, DD, DD);

  gemmt<1><<<dim3(NKV / 128, 32), blk, 0, stream>>>(xb, WqkvT, QKVb, NKV, DD);
  rope2k<<<BB * TT, blk, 0, stream>>>(QKVb);
  vtrans<<<dim3(32, 8, BB), blk, 0, stream>>>(QKVb, Vt);
  attn4<<<dim3(32, HH, BB), blk, 0, stream>>>(QKVb, Vt, Ob);
  gemmt<0><<<dim3(DD / 128, 32), blk, 0, stream>>>(Ob, WoT, out, DD, DD);
}